// Round 12
// baseline (1726.017 us; speedup 1.0000x reference)
//
#include <hip/hip_runtime.h>
#include <hip/hip_bf16.h>

#define HH 51
#define TPB 512     // 8 waves; 1 block/CU. Encode: fused 1-phase/step. Feedback: short-P1 + fused-e2-P2.
#define BPB 8
#define US 36       // unit stride (floats) in gbuf1

typedef _Float16 half8 __attribute__((ext_vector_type(8)));
typedef float f4 __attribute__((ext_vector_type(4)));

// Light barrier: drain LDS only; global stores / reg-dest loads stay in flight.
#define LBAR() asm volatile("s_waitcnt lgkmcnt(0)\ns_barrier" ::: "memory")

__device__ __forceinline__ float bf2f(unsigned short u) {
    return __uint_as_float(((unsigned)u) << 16);
}
__device__ __forceinline__ float loadf(const void* p, size_t i, bool bf) {
    return bf ? bf2f(((const unsigned short*)p)[i]) : ((const float*)p)[i];
}
__device__ __forceinline__ void storef(void* p, size_t i, float v, bool bf) {
    if (bf) ((__hip_bfloat16*)p)[i] = __float2bfloat16(v);
    else    ((float*)p)[i] = v;
}
__device__ __forceinline__ float sigm(float v) {
    return __builtin_amdgcn_rcpf(1.0f + __expf(-v));
}
__device__ __forceinline__ float tanh_fast(float v) {
    return fmaf(2.0f, __builtin_amdgcn_rcpf(1.0f + __expf(-2.0f * v)), -1.0f);
}
__device__ __forceinline__ f4 MF(half8 a, half8 b, f4 c) {
    return __builtin_amdgcn_mfma_f32_16x16x32_f16(a, b, c, 0, 0, 0);
}
__device__ __forceinline__ float rdlane(float v, int idx) {
    return __builtin_bit_cast(float, __builtin_amdgcn_readlane(__builtin_bit_cast(int, v), idx));
}

__global__ __launch_bounds__(TPB, 1) void gru_kernel(
    const void* __restrict__ xg,
    const void* __restrict__ wih1, const void* __restrict__ whh1,
    const void* __restrict__ bih1, const void* __restrict__ bhh1,
    const void* __restrict__ wih2, const void* __restrict__ whh2,
    const void* __restrict__ bih2, const void* __restrict__ bhh2,
    const void* __restrict__ wlin, const void* __restrict__ blin_p,
    void* __restrict__ dout, int T, int TF)
{
    // Rows 4-interleaved: staged row r = 4*unit + slot.
    //  M1: (r_full, z_full, n_h, n_i) — wih1 col53, biases col52, Whh1 cols 0-50
    //  M2: (r2, z2, n2_h, n2_i) over K=128: [h2|bias ; h1]; out row 204 (wl, blv@52)
    __shared__ __align__(16) _Float16 stg[208 * 64];     // 26624 B
    __shared__ __align__(16) float gbuf1[52 * US];       // feedback layer-1 gates
    __shared__ __align__(16) _Float16 h1T[2][16 * 72];   // double-buffered h1; k52=1, k53=x-fold
    __shared__ __align__(16) _Float16 h2T[2][16 * 72];   // double-buffered h2; k52=1
    __shared__ __align__(16) float obufL[BPB * 64];      // out ring
    __shared__ __align__(16) float opart[BPB * 8];       // out partials [batch][wave]
    __shared__ __align__(16) float hfin[BPB * 52];       // f32 h1 handoff at transition

    const int tid = threadIdx.x, w = tid >> 6, lane = tid & 63;
    const int n16 = lane & 15, q = lane >> 4;
    const bool li = lane < HH;
    const int il = li ? lane : HH - 1;
    const int bg0 = blockIdx.x * BPB;
    const int myb = bg0 + w;

    // runtime dtype detection (fp32 vs bf16), uniform
    bool isbf;
    {
        const unsigned short* u = (const unsigned short*)whh1;
        int ok = 1;
#pragma unroll
        for (int k = 0; k < 16; ++k) {
            unsigned e = (u[2 * k] >> 7) & 0xFF;
            ok &= (e >= 100 && e <= 125) ? 1 : 0;
        }
        isbf = (ok != 0);
    }

    // lane consts (feedback P1 + out partials)
    float wr1 = 0, wz1 = 0, wn1 = 0;
    if (li) {
        wr1 = loadf(wih1, il, isbf);  wz1 = loadf(wih1, HH + il, isbf);
        wn1 = loadf(wih1, 2 * HH + il, isbf);
    }
    const float blv = loadf(blin_p, 0, isbf);

    // ---- balanced job tables (shared encode+feedback): per-wave MFMA = 10,10,10,10,10,10,10,8
    // M1: w<5:{w}; w5:{5,6,7}; w6:{8,9,10}; w7:{11,12}. M2: w<5:{2w,2w+1}; w>=5:{w+5}.
    const int nm1 = (w < 5) ? 1 : (w < 7) ? 3 : 2;
    const int bm1 = (w < 5) ? w : 5 + (w - 5) * 3;
    int m1t[3] = { bm1, bm1 + 1, bm1 + 2 };
    const int nm2 = (w < 5) ? 2 : 1;
    int m2t[2] = { (w < 5) ? 2 * w : w + 5, (w < 5) ? 2 * w + 1 : 0 };
    const int laneoff = q * US + 4 * n16;
    const bool stlane = (n16 < 8);
    const bool outw = (w == 7);   // M2 job i==0 is tile 12 (out row)

    // per-lane wl for M2 units (partials)
    float wlc[2] = { 0.f, 0.f };
#pragma unroll
    for (int i = 0; i < 2; ++i) if (i < nm2) {
        int u = 4 * m2t[i] + q;
        if (u < HH) wlc[i] = loadf(wlin, u, isbf);
    }

    half8 WfM1[3][2], WfM2[2][4];

    // ---- stage: pass0 = M1; pass1 = M2 K 0-63 (h2 half); pass2 = M2 K 64-127 (h1 half) ----
#pragma unroll 1
    for (int ps = 0; ps < 3; ++ps) {
        for (int e = tid; e < 208 * 64; e += TPB) {
            int r = e >> 6, k = e & 63;
            int u = r >> 2, g = r & 3;
            float v = 0.0f;
            if (ps == 0) {
                if (u < HH) {
                    if (g < 2) {
                        int gr = g * HH + u;
                        if (k < HH) v = loadf(whh1, (size_t)gr * HH + k, isbf);
                        else if (k == 52) v = loadf(bhh1, gr, isbf) + loadf(bih1, gr, isbf);
                        else if (k == 53) v = loadf(wih1, gr, isbf);
                    } else if (g == 2) {
                        int gr = 2 * HH + u;
                        if (k < HH) v = loadf(whh1, (size_t)gr * HH + k, isbf);
                        else if (k == 52) v = loadf(bhh1, gr, isbf);
                    } else {
                        int gr = 2 * HH + u;
                        if (k == 52) v = loadf(bih1, gr, isbf);
                        else if (k == 53) v = loadf(wih1, gr, isbf);
                    }
                }
            } else if (ps == 1) {
                if (u < HH) {
                    if (g < 2) {
                        int gr = g * HH + u;
                        if (k < HH) v = loadf(whh2, (size_t)gr * HH + k, isbf);
                        else if (k == 52) v = loadf(bhh2, gr, isbf) + loadf(bih2, gr, isbf);
                    } else if (g == 2) {
                        int gr = 2 * HH + u;
                        if (k < HH) v = loadf(whh2, (size_t)gr * HH + k, isbf);
                        else if (k == 52) v = loadf(bhh2, gr, isbf);
                    } else {
                        if (k == 52) v = loadf(bih2, 2 * HH + u, isbf);
                    }
                } else if (r == 204) {   // out row: wl . h2 + blv
                    if (k < HH) v = loadf(wlin, k, isbf);
                    else if (k == 52) v = blv;
                }
            } else {
                if (u < HH) {
                    if (g < 2) {
                        if (k < HH) v = loadf(wih2, (size_t)(g * HH + u) * HH + k, isbf);
                    } else if (g == 3) {
                        if (k < HH) v = loadf(wih2, (size_t)(2 * HH + u) * HH + k, isbf);
                    }
                }
            }
            stg[e] = (_Float16)v;
        }
        __syncthreads();
        if (ps == 0) {
#pragma unroll
            for (int i = 0; i < 3; ++i) if (i < nm1) {
                int tl = m1t[i];
                WfM1[i][0] = *(const half8*)(stg + (size_t)(16 * tl + n16) * 64 + q * 8);
                WfM1[i][1] = *(const half8*)(stg + (size_t)(16 * tl + n16) * 64 + 32 + q * 8);
            }
        } else if (ps == 1) {
#pragma unroll
            for (int i = 0; i < 2; ++i) if (i < nm2) {
                int tl = m2t[i];
                WfM2[i][0] = *(const half8*)(stg + (size_t)(16 * tl + n16) * 64 + q * 8);
                WfM2[i][1] = *(const half8*)(stg + (size_t)(16 * tl + n16) * 64 + 32 + q * 8);
            }
        } else {
#pragma unroll
            for (int i = 0; i < 2; ++i) if (i < nm2) {
                int tl = m2t[i];
                WfM2[i][2] = *(const half8*)(stg + (size_t)(16 * tl + n16) * 64 + q * 8);
                WfM2[i][3] = *(const half8*)(stg + (size_t)(16 * tl + n16) * 64 + 32 + q * 8);
            }
        }
        __syncthreads();
    }

    // ---- init state LDS ----
    for (int e = tid; e < 16 * 72; e += TPB) {
        h1T[0][e] = (_Float16)0; h1T[1][e] = (_Float16)0;
        h2T[0][e] = (_Float16)0; h2T[1][e] = (_Float16)0;
    }
    float xreg = 0.0f, xnext = 0.0f;
    if (lane < T) xreg = loadf(xg, (size_t)myb * T + lane, isbf);
    __syncthreads();
    if (tid < 16) {
        h1T[0][tid * 72 + 52] = (_Float16)1.0f; h1T[1][tid * 72 + 52] = (_Float16)1.0f;
        h2T[0][tid * 72 + 52] = (_Float16)1.0f; h2T[1][tid * 72 + 52] = (_Float16)1.0f;
    }
    if (lane == 0) h1T[1][w * 72 + 53] = (_Float16)rdlane(xreg, 0);   // x(0) into phase-0 read buffer
    __syncthreads();

    float h1s[3] = {0.f, 0.f, 0.f}, h2s[2] = {0.f, 0.f};

    // ================= ENCODE: one fused phase per step =================
    for (int t = 0; t < T; ++t) {
        const _Float16* h1r = h1T[(t + 1) & 1];
        const _Float16* h2r = h2T[(t + 1) & 1];
        _Float16* h1w = h1T[t & 1];
        _Float16* h2w = h2T[t & 1];
        half8 H10 = *(const half8*)(h1r + n16 * 72 + q * 8);
        half8 H11 = *(const half8*)(h1r + n16 * 72 + 32 + q * 8);
        half8 H20 = *(const half8*)(h2r + n16 * 72 + q * 8);
        half8 H21 = *(const half8*)(h2r + n16 * 72 + 32 + q * 8);
        // x(t+1) fold into next read buffer
        {
            int ni = (t + 1) & 63;
            float xsrc = (ni == 0) ? xnext : xreg;
            float xnv = (t == T - 1) ? 0.0f : rdlane(xsrc, ni);
            if (lane == 0) h1w[w * 72 + 53] = (_Float16)xnv;
        }
#pragma unroll
        for (int i = 0; i < 3; ++i) if (i < nm1) {
            f4 a = {0.f, 0.f, 0.f, 0.f};
            a = MF(WfM1[i][0], H10, a); a = MF(WfM1[i][1], H11, a);
            float r = sigm(a[0]), z = sigm(a[1]);
            float n = tanh_fast(fmaf(r, a[2], a[3]));
            float h = fmaf(z, h1s[i] - n, n); h1s[i] = h;
            int u = 4 * m1t[i] + q;
            if (n16 < 8 && u < HH) h1w[n16 * 72 + u] = (_Float16)h;
        }
#pragma unroll
        for (int i = 0; i < 2; ++i) if (i < nm2) {
            f4 a = {0.f, 0.f, 0.f, 0.f}, b = {0.f, 0.f, 0.f, 0.f};
            a = MF(WfM2[i][0], H20, a); a = MF(WfM2[i][1], H21, a);
            b = MF(WfM2[i][2], H10, b); b = MF(WfM2[i][3], H11, b);
            a = a + b;
            if (t > 0) {
                if (outw && i == 0 && q == 3 && n16 < 8 && t >= 2)
                    obufL[n16 * 64 + ((t - 2) & 63)] = a[0];   // out(t-2) from fold row
                float r2 = sigm(a[0]), z2 = sigm(a[1]);
                float n2 = tanh_fast(fmaf(r2, a[2], a[3]));
                float h = fmaf(z2, h2s[i] - n2, n2); h2s[i] = h;
                int u = 4 * m2t[i] + q;
                if (n16 < 8 && u < HH) h2w[n16 * 72 + u] = (_Float16)h;
            }
        }
        // waves 5,6 flush outputs [t-34 .. t-3]
        if ((w == 5 || w == 6) && (t & 31) == 2 && t >= 34) {
            int fb = t - 34;
#pragma unroll
            for (int k2 = 0; k2 < 2; ++k2) {
                int et = ((w - 5) << 7) + (k2 << 6) + lane;
                int b2 = et >> 5, tt = et & 31;
                storef(dout, (size_t)(bg0 + b2) * TF + fb + tt, obufL[b2 * 64 + ((fb + tt) & 63)], isbf);
            }
        }
        // x double-buffer
        if ((t & 63) == 0) {
            int base = t + 64;
            if (base < T) {
                int src = base + lane;
                xnext = (src < T) ? loadf(xg, (size_t)myb * T + src, isbf) : 0.0f;
            }
        } else if ((t & 63) == 63) {
            xreg = xnext;
        }
        LBAR();
    }

    // ================= TRANSITION (plays the role of feedback P2(T-1)) =================
    const int fbi = (T + 1) & 1;   // == (T-1)&1
    {
        const _Float16* h1r = h1T[fbi];            // h1(T-1), bias, x=0
        const _Float16* h2r = h2T[fbi];            // h2(T-2)
        half8 H10 = *(const half8*)(h1r + n16 * 72 + q * 8);
        half8 H11 = *(const half8*)(h1r + n16 * 72 + 32 + q * 8);
        half8 H20 = *(const half8*)(h2r + n16 * 72 + q * 8);
        half8 H21 = *(const half8*)(h2r + n16 * 72 + 32 + q * 8);
        _Float16* h2wn = h2T[T & 1];               // h2(T-1) -> read by P2(T)
#pragma unroll
        for (int i = 0; i < 3; ++i) if (i < nm1) {
            f4 a = {0.f, 0.f, 0.f, 0.f};
            a = MF(WfM1[i][0], H10, a); a = MF(WfM1[i][1], H11, a);
            if (stlane) *(f4*)(gbuf1 + m1t[i] * 4 * US + laneoff) = a;   // G1(T)
            int u = 4 * m1t[i] + q;
            if (n16 < 8 && u < HH) hfin[n16 * 52 + u] = h1s[i];          // h1(T-1) f32
        }
        float po = 0.0f;
#pragma unroll
        for (int i = 0; i < 2; ++i) if (i < nm2) {
            f4 a = {0.f, 0.f, 0.f, 0.f}, b = {0.f, 0.f, 0.f, 0.f};
            a = MF(WfM2[i][0], H20, a); a = MF(WfM2[i][1], H21, a);
            b = MF(WfM2[i][2], H10, b); b = MF(WfM2[i][3], H11, b);
            a = a + b;
            if (outw && i == 0 && q == 3 && n16 < 8)
                obufL[n16 * 64 + ((T - 2) & 63)] = a[0];   // out(T-2) patch
            float r2 = sigm(a[0]), z2 = sigm(a[1]);        // fused e2(T-1)
            float n2 = tanh_fast(fmaf(r2, a[2], a[3]));
            float h = fmaf(z2, h2s[i] - n2, n2); h2s[i] = h;
            int u = 4 * m2t[i] + q;
            if (n16 < 8 && u < HH) h2wn[n16 * 72 + u] = (_Float16)h;
            po += h * wlc[i];
        }
        po += __shfl_xor(po, 16);
        po += __shfl_xor(po, 32);
        if (lane < 8) opart[lane * 8 + w] = po;   // partials of out(T-1)
    }
    __syncthreads();

    float h1p = hfin[w * 52 + il];   // h1(T-1) for batch w
    const float* gl1 = gbuf1 + il * US + 4 * w;
    _Float16* fh1 = h1T[fbi];

    // ================= FEEDBACK: short P1 + fused-e2 P2 =================
    for (int t = T; t < TF; ++t) {
        // ---- P1: out(t-1) from partials -> e1(t) ----
        f4 G1 = *(const f4*)gl1;
        f4 pa = *(const f4*)(opart + w * 8);
        f4 pb = *(const f4*)(opart + w * 8 + 4);
        float outv = ((pa[0] + pa[1]) + (pa[2] + pa[3])) + ((pb[0] + pb[1]) + (pb[2] + pb[3])) + blv;
        if (lane == 0) obufL[w * 64 + ((t - 1) & 63)] = outv;
        {
            float r = sigm(fmaf(outv, wr1, G1[0]));
            float z = sigm(fmaf(outv, wz1, G1[1]));
            float n = tanh_fast(fmaf(r, G1[2], fmaf(outv, wn1, G1[3])));   // G1[3] = bin
            float h1 = fmaf(z, h1p - n, n); h1p = h1;
            if (li) fh1[w * 72 + il] = (_Float16)h1;
        }
        LBAR();
        // ---- P2: MFMAs; fused e2(t); partials of out(t) ----
        {
            half8 H10 = *(const half8*)(fh1 + n16 * 72 + q * 8);           // h1(t)
            half8 H11 = *(const half8*)(fh1 + n16 * 72 + 32 + q * 8);
            const _Float16* h2r = h2T[t & 1];                              // h2(t-1)
            half8 H20 = *(const half8*)(h2r + n16 * 72 + q * 8);
            half8 H21 = *(const half8*)(h2r + n16 * 72 + 32 + q * 8);
            _Float16* h2wn = h2T[(t + 1) & 1];                             // h2(t)
#pragma unroll
            for (int i = 0; i < 3; ++i) if (i < nm1) {
                f4 a = {0.f, 0.f, 0.f, 0.f};
                a = MF(WfM1[i][0], H10, a); a = MF(WfM1[i][1], H11, a);
                if (stlane) *(f4*)(gbuf1 + m1t[i] * 4 * US + laneoff) = a; // G1(t+1)
            }
            float po = 0.0f;
#pragma unroll
            for (int i = 0; i < 2; ++i) if (i < nm2) {
                f4 a = {0.f, 0.f, 0.f, 0.f}, b = {0.f, 0.f, 0.f, 0.f};
                a = MF(WfM2[i][0], H20, a); a = MF(WfM2[i][1], H21, a);
                b = MF(WfM2[i][2], H10, b); b = MF(WfM2[i][3], H11, b);
                a = a + b;
                float r2 = sigm(a[0]), z2 = sigm(a[1]);                    // fused e2(t)
                float n2 = tanh_fast(fmaf(r2, a[2], a[3]));
                float h = fmaf(z2, h2s[i] - n2, n2); h2s[i] = h;
                int u = 4 * m2t[i] + q;
                if (n16 < 8 && u < HH) h2wn[n16 * 72 + u] = (_Float16)h;
                po += h * wlc[i];
            }
            po += __shfl_xor(po, 16);
            po += __shfl_xor(po, 32);
            if (lane < 8) opart[lane * 8 + w] = po;                        // partials of out(t)
        }
        if ((w == 5 || w == 6) && (t & 31) == 0) {   // flush [t-32 .. t-1]
            int fb = t - 32;
#pragma unroll
            for (int k2 = 0; k2 < 2; ++k2) {
                int et = ((w - 5) << 7) + (k2 << 6) + lane;
                int b2 = et >> 5, tt = et & 31;
                storef(dout, (size_t)(bg0 + b2) * TF + fb + tt, obufL[b2 * 64 + ((fb + tt) & 63)], isbf);
            }
        }
        LBAR();
    }

    // ---- epilogue: out(TF-1) from partials + tail flush ----
    {
        f4 pa = *(const f4*)(opart + w * 8);
        f4 pb = *(const f4*)(opart + w * 8 + 4);
        float outv = ((pa[0] + pa[1]) + (pa[2] + pa[3])) + ((pb[0] + pb[1]) + (pb[2] + pb[3])) + blv;
        if (lane == 0) obufL[w * 64 + ((TF - 1) & 63)] = outv;
    }
    __syncthreads();
    {
        int base = (TF - 1) & ~31, rem = TF - base;
        if (tid < BPB * 32) {
            int b2 = tid >> 5, tt = tid & 31;
            if (tt < rem)
                storef(dout, (size_t)(bg0 + b2) * TF + base + tt, obufL[b2 * 64 + ((base + tt) & 63)], isbf);
        }
    }
}

extern "C" void kernel_launch(void* const* d_in, const int* in_sizes, int n_in,
                              void* d_out, int out_size, void* d_ws, size_t ws_size,
                              hipStream_t stream) {
    const int B = 2048;
    const int T = in_sizes[0] / B;   // 1000
    const int TF = out_size / B;     // 2000
    gru_kernel<<<dim3(B / BPB), dim3(TPB), 0, stream>>>(
        d_in[0], d_in[1], d_in[2], d_in[3], d_in[4], d_in[5],
        d_in[6], d_in[7], d_in[8], d_in[9], d_in[10],
        d_out, T, TF);
}

// Round 13
// 1463.286 us; speedup vs baseline: 1.1795x; 1.1795x over previous
//
#include <hip/hip_runtime.h>
#include <hip/hip_bf16.h>

#define HH 51
#define TPB 512     // 8 waves; 1 block/CU. Encode: fused 1-phase/step (unrolled x2). Feedback: R9/R11 2-phase.
#define BPB 8
#define US 36       // unit stride (floats) in gate buffers (feedback path)

typedef _Float16 half8 __attribute__((ext_vector_type(8)));
typedef float f4 __attribute__((ext_vector_type(4)));

// Light barrier: drain LDS only; global stores / reg-dest loads stay in flight.
#define LBAR() asm volatile("s_waitcnt lgkmcnt(0)\ns_barrier" ::: "memory")

__device__ __forceinline__ float bf2f(unsigned short u) {
    return __uint_as_float(((unsigned)u) << 16);
}
__device__ __forceinline__ float loadf(const void* p, size_t i, bool bf) {
    return bf ? bf2f(((const unsigned short*)p)[i]) : ((const float*)p)[i];
}
__device__ __forceinline__ void storef(void* p, size_t i, float v, bool bf) {
    if (bf) ((__hip_bfloat16*)p)[i] = __float2bfloat16(v);
    else    ((float*)p)[i] = v;
}
__device__ __forceinline__ float sigm(float v) {
    return __builtin_amdgcn_rcpf(1.0f + __expf(-v));
}
__device__ __forceinline__ float tanh_fast(float v) {
    return fmaf(2.0f, __builtin_amdgcn_rcpf(1.0f + __expf(-2.0f * v)), -1.0f);
}
__device__ __forceinline__ f4 MF(half8 a, half8 b, f4 c) {
    return __builtin_amdgcn_mfma_f32_16x16x32_f16(a, b, c, 0, 0, 0);
}
// wave64 sum via DPP (verified), result uniform across lanes
__device__ __forceinline__ float wave_sum(float x) {
    float s = x, t;
    t = __builtin_bit_cast(float, __builtin_amdgcn_update_dpp(0, __builtin_bit_cast(int, s), 0x111, 0xf, 0xf, true)); s += t;
    t = __builtin_bit_cast(float, __builtin_amdgcn_update_dpp(0, __builtin_bit_cast(int, s), 0x112, 0xf, 0xf, true)); s += t;
    t = __builtin_bit_cast(float, __builtin_amdgcn_update_dpp(0, __builtin_bit_cast(int, s), 0x114, 0xf, 0xf, true)); s += t;
    t = __builtin_bit_cast(float, __builtin_amdgcn_update_dpp(0, __builtin_bit_cast(int, s), 0x118, 0xf, 0xf, true)); s += t;
    t = __builtin_bit_cast(float, __builtin_amdgcn_update_dpp(0, __builtin_bit_cast(int, s), 0x142, 0xa, 0xf, true)); s += t;
    t = __builtin_bit_cast(float, __builtin_amdgcn_update_dpp(0, __builtin_bit_cast(int, s), 0x143, 0xc, 0xf, true)); s += t;
    return __builtin_bit_cast(float, __builtin_amdgcn_readlane(__builtin_bit_cast(int, s), 63));
}
__device__ __forceinline__ float rdlane(float v, int idx) {
    return __builtin_bit_cast(float, __builtin_amdgcn_readlane(__builtin_bit_cast(int, v), idx));
}

__global__ __launch_bounds__(TPB, 1) void gru_kernel(
    const void* __restrict__ xg,
    const void* __restrict__ wih1, const void* __restrict__ whh1,
    const void* __restrict__ bih1, const void* __restrict__ bhh1,
    const void* __restrict__ wih2, const void* __restrict__ whh2,
    const void* __restrict__ bih2, const void* __restrict__ bhh2,
    const void* __restrict__ wlin, const void* __restrict__ blin_p,
    void* __restrict__ dout, int T, int TF)
{
    // Rows 4-interleaved: staged row r = 4*unit + slot.
    //  M1: (r_full, z_full, n_h, n_i) — wih1 col53, biases col52, Whh1 cols 0-50
    //  M2: (r2, z2, n2_h, n2_i) over K=128: [h2|bias ; h1]; out row 204 (wl, blv@52)
    __shared__ __align__(16) _Float16 stg[208 * 64];     // 26624 B
    __shared__ __align__(16) float gbuf1[52 * US];       // feedback gates layer 1
    __shared__ __align__(16) float gbuf2[52 * US];       // feedback gates layer 2 (+ out @ unit 51)
    __shared__ __align__(16) _Float16 h1T[2][16 * 72];   // double-buffered h1; k52=1, k53=x-fold
    __shared__ __align__(16) _Float16 h2T[2][16 * 72];   // double-buffered h2; k52=1
    __shared__ float obufL[BPB * 64];                    // out ring, 64 deep
    __shared__ float hfin[2][BPB * 52];                  // f32 h-state handoff at transition

    const int tid = threadIdx.x, w = tid >> 6, lane = tid & 63;
    const int n16 = lane & 15, q = lane >> 4;
    const bool li = lane < HH;
    const int il = li ? lane : HH - 1;
    const int bg0 = blockIdx.x * BPB;
    const int myb = bg0 + w;

    // runtime dtype detection (fp32 vs bf16), uniform
    bool isbf;
    {
        const unsigned short* u = (const unsigned short*)whh1;
        int ok = 1;
#pragma unroll
        for (int k = 0; k < 16; ++k) {
            unsigned e = (u[2 * k] >> 7) & 0xFF;
            ok &= (e >= 100 && e <= 125) ? 1 : 0;
        }
        isbf = (ok != 0);
    }

    // lane consts (feedback path + out)
    float wr1 = 0, wz1 = 0, wn1 = 0, wl = 0;
    if (li) {
        wr1 = loadf(wih1, il, isbf);          wz1 = loadf(wih1, HH + il, isbf);
        wn1 = loadf(wih1, 2 * HH + il, isbf); wl = loadf(wlin, il, isbf);
    }
    const float blv = loadf(blin_p, 0, isbf);

    // ---- job assignment (R11 tables, proven): 13 M1 + 13 M2 tiles over 8 waves ----
    const int nm1 = (w < 5) ? 2 : 1;
    int m2a, m2b, nm2;
    if (w < 2)      { m2a = w + 3; m2b = w + 11; nm2 = 2; }
    else if (w < 5) { m2a = w + 3; m2b = 0;      nm2 = 1; }
    else            { m2a = w - 5; m2b = w + 3;  nm2 = 2; }
    const int m1t[2] = { w, w + 8 };
    const int m2t[2] = { m2a, m2b };
    const int laneoff = q * US + 4 * n16;
    const bool stlane = (n16 < 8);
    const bool outw = (w == 1);   // owns M2 tile 12 (out row) at i==1

    half8 WfM1[2][2], WfM2[2][4];

    // ---- stage: pass0 = M1; pass1 = M2 K 0-63 (h2 half); pass2 = M2 K 64-127 (h1 half) ----
#pragma unroll 1
    for (int ps = 0; ps < 3; ++ps) {
        for (int e = tid; e < 208 * 64; e += TPB) {
            int r = e >> 6, k = e & 63;
            int u = r >> 2, g = r & 3;
            float v = 0.0f;
            if (ps == 0) {
                if (u < HH) {
                    if (g < 2) {
                        int gr = g * HH + u;
                        if (k < HH) v = loadf(whh1, (size_t)gr * HH + k, isbf);
                        else if (k == 52) v = loadf(bhh1, gr, isbf) + loadf(bih1, gr, isbf);
                        else if (k == 53) v = loadf(wih1, gr, isbf);
                    } else if (g == 2) {
                        int gr = 2 * HH + u;
                        if (k < HH) v = loadf(whh1, (size_t)gr * HH + k, isbf);
                        else if (k == 52) v = loadf(bhh1, gr, isbf);
                    } else {
                        int gr = 2 * HH + u;
                        if (k == 52) v = loadf(bih1, gr, isbf);
                        else if (k == 53) v = loadf(wih1, gr, isbf);
                    }
                }
            } else if (ps == 1) {
                if (u < HH) {
                    if (g < 2) {
                        int gr = g * HH + u;
                        if (k < HH) v = loadf(whh2, (size_t)gr * HH + k, isbf);
                        else if (k == 52) v = loadf(bhh2, gr, isbf) + loadf(bih2, gr, isbf);
                    } else if (g == 2) {
                        int gr = 2 * HH + u;
                        if (k < HH) v = loadf(whh2, (size_t)gr * HH + k, isbf);
                        else if (k == 52) v = loadf(bhh2, gr, isbf);
                    } else {
                        if (k == 52) v = loadf(bih2, 2 * HH + u, isbf);
                    }
                } else if (r == 204) {   // out row: wl . h2 + blv
                    if (k < HH) v = loadf(wlin, k, isbf);
                    else if (k == 52) v = blv;
                }
            } else {
                if (u < HH) {
                    if (g < 2) {
                        if (k < HH) v = loadf(wih2, (size_t)(g * HH + u) * HH + k, isbf);
                    } else if (g == 3) {
                        if (k < HH) v = loadf(wih2, (size_t)(2 * HH + u) * HH + k, isbf);
                    }
                }
            }
            stg[e] = (_Float16)v;
        }
        __syncthreads();
        if (ps == 0) {
#pragma unroll
            for (int i = 0; i < 2; ++i) if (i < nm1) {
                int tl = m1t[i];
                WfM1[i][0] = *(const half8*)(stg + (size_t)(16 * tl + n16) * 64 + q * 8);
                WfM1[i][1] = *(const half8*)(stg + (size_t)(16 * tl + n16) * 64 + 32 + q * 8);
            }
        } else if (ps == 1) {
#pragma unroll
            for (int i = 0; i < 2; ++i) if (i < nm2) {
                int tl = m2t[i];
                WfM2[i][0] = *(const half8*)(stg + (size_t)(16 * tl + n16) * 64 + q * 8);
                WfM2[i][1] = *(const half8*)(stg + (size_t)(16 * tl + n16) * 64 + 32 + q * 8);
            }
        } else {
#pragma unroll
            for (int i = 0; i < 2; ++i) if (i < nm2) {
                int tl = m2t[i];
                WfM2[i][2] = *(const half8*)(stg + (size_t)(16 * tl + n16) * 64 + q * 8);
                WfM2[i][3] = *(const half8*)(stg + (size_t)(16 * tl + n16) * 64 + 32 + q * 8);
            }
        }
        __syncthreads();
    }

    // ---- init state LDS ----
    for (int e = tid; e < 16 * 72; e += TPB) {
        h1T[0][e] = (_Float16)0; h1T[1][e] = (_Float16)0;
        h2T[0][e] = (_Float16)0; h2T[1][e] = (_Float16)0;
    }
    float xreg = 0.0f, xnext = 0.0f;
    if (lane < T) xreg = loadf(xg, (size_t)myb * T + lane, isbf);
    __syncthreads();
    if (tid < 16) {
        h1T[0][tid * 72 + 52] = (_Float16)1.0f; h1T[1][tid * 72 + 52] = (_Float16)1.0f;
        h2T[0][tid * 72 + 52] = (_Float16)1.0f; h2T[1][tid * 72 + 52] = (_Float16)1.0f;
    }
    if (lane == 0) h1T[1][w * 72 + 53] = (_Float16)rdlane(xreg, 0);   // x(0) into phase-0 read buffer
    __syncthreads();

    float h1s[2] = {0.f, 0.f}, h2s[2] = {0.f, 0.f};

    // ---- hoisted lane-invariant offsets/masks ----
    const int ro0 = n16 * 72 + q * 8, ro1 = ro0 + 32;
    int wo1[2], wo2[2];
    bool stw1[2], stw2[2];
#pragma unroll
    for (int i = 0; i < 2; ++i) {
        int u1 = 4 * m1t[i] + q, u2 = 4 * m2t[i] + q;
        wo1[i] = n16 * 72 + u1; stw1[i] = (n16 < 8) && (u1 < HH);
        wo2[i] = n16 * 72 + u2; stw2[i] = (n16 < 8) && (u2 < HH);
    }
    const bool obl = outw && (q == 3) && (n16 < 8);
    const int s1o[2] = { m1t[0] * 4 * US + laneoff, m1t[1] * 4 * US + laneoff };
    const int s2o[2] = { m2t[0] * 4 * US + laneoff, m2t[1] * 4 * US + laneoff };

// fused encode step body; buffer pointers are compile-time per call site
#define ENC_BODY(T_, H1R, H2R, H1W, H2W, DOM2, DOOUT)                          \
    {                                                                          \
        half8 H10 = *(const half8*)((H1R) + ro0);                              \
        half8 H11 = *(const half8*)((H1R) + ro1);                              \
        half8 H20 = *(const half8*)((H2R) + ro0);                              \
        half8 H21 = *(const half8*)((H2R) + ro1);                              \
        {                                                                      \
            int ni = ((T_) + 1) & 63;                                          \
            float xsrc = (ni == 0) ? xnext : xreg;                             \
            float xnv = ((T_) == T - 1) ? 0.0f : rdlane(xsrc, ni);             \
            if (lane == 0) (H1W)[w * 72 + 53] = (_Float16)xnv;                 \
        }                                                                      \
        _Pragma("unroll")                                                      \
        for (int i = 0; i < 2; ++i) if (i < nm1) {                             \
            f4 a = {0.f, 0.f, 0.f, 0.f};                                       \
            a = MF(WfM1[i][0], H10, a); a = MF(WfM1[i][1], H11, a);            \
            float r = sigm(a[0]), z = sigm(a[1]);                              \
            float n = tanh_fast(fmaf(r, a[2], a[3]));                          \
            float h = fmaf(z, h1s[i] - n, n); h1s[i] = h;                      \
            if (stw1[i]) (H1W)[wo1[i]] = (_Float16)h;                          \
        }                                                                      \
        if (DOM2) {                                                            \
            _Pragma("unroll")                                                  \
            for (int i = 0; i < 2; ++i) if (i < nm2) {                         \
                f4 a = {0.f, 0.f, 0.f, 0.f}, b = {0.f, 0.f, 0.f, 0.f};         \
                a = MF(WfM2[i][0], H20, a); a = MF(WfM2[i][1], H21, a);        \
                b = MF(WfM2[i][2], H10, b); b = MF(WfM2[i][3], H11, b);        \
                a = a + b;                                                     \
                if ((DOOUT) && i == 1 && obl)                                  \
                    obufL[n16 * 64 + (((T_) - 2) & 63)] = a[0];                \
                float r2 = sigm(a[0]), z2 = sigm(a[1]);                        \
                float n2 = tanh_fast(fmaf(r2, a[2], a[3]));                    \
                float h = fmaf(z2, h2s[i] - n2, n2); h2s[i] = h;               \
                if (stw2[i]) (H2W)[wo2[i]] = (_Float16)h;                      \
            }                                                                  \
        }                                                                      \
    }

    // ================= ENCODE (unrolled x2; T even) =================
    // peel t = 0 (M2 is dead) and t = 1 (M2 active, no out write)
    ENC_BODY(0, h1T[1], h2T[1], h1T[0], h2T[0], false, false);
    if (64 < T) {   // (0&63)==0 x-window load for base 64
        int src = 64 + lane;
        xnext = (src < T) ? loadf(xg, (size_t)myb * T + src, isbf) : 0.0f;
    }
    LBAR();
    ENC_BODY(1, h1T[0], h2T[0], h1T[1], h2T[1], true, false);
    LBAR();
    for (int t = 2; t < T; t += 2) {
        // even copy: reads buf1, writes buf0; x-load check; flush check
        ENC_BODY(t, h1T[1], h2T[1], h1T[0], h2T[0], true, true);
        if (w >= 6 && (t & 31) == 2 && t >= 34) {   // flush [t-34 .. t-3]
            int fb = t - 34;
#pragma unroll
            for (int k2 = 0; k2 < 2; ++k2) {
                int et = ((w - 6) << 7) + (k2 << 6) + lane;
                int b2 = et >> 5, tt = et & 31;
                storef(dout, (size_t)(bg0 + b2) * TF + fb + tt, obufL[b2 * 64 + ((fb + tt) & 63)], isbf);
            }
        }
        if ((t & 63) == 0) {
            int base = t + 64;
            if (base < T) {
                int src = base + lane;
                xnext = (src < T) ? loadf(xg, (size_t)myb * T + src, isbf) : 0.0f;
            }
        }
        LBAR();
        // odd copy: reads buf0, writes buf1; x-swap check
        ENC_BODY(t + 1, h1T[0], h2T[0], h1T[1], h2T[1], true, true);
        if (((t + 1) & 63) == 63) xreg = xnext;
        LBAR();
    }

    // ================= TRANSITION: populate gbuf + f32 h-state handoff =================
    const int fbi = (T + 1) & 1;   // == (T-1)&1
    {
        const _Float16* h1r = h1T[fbi];
        const _Float16* h2r = h2T[fbi];
        half8 H10 = *(const half8*)(h1r + ro0);
        half8 H11 = *(const half8*)(h1r + ro1);
        half8 H20 = *(const half8*)(h2r + ro0);
        half8 H21 = *(const half8*)(h2r + ro1);
#pragma unroll
        for (int i = 0; i < 2; ++i) if (i < nm1) {
            f4 a = {0.f, 0.f, 0.f, 0.f};
            a = MF(WfM1[i][0], H10, a); a = MF(WfM1[i][1], H11, a);
            if (stlane) *(f4*)(gbuf1 + s1o[i]) = a;                  // G1(T)
            int u = 4 * m1t[i] + q;
            if (n16 < 8 && u < HH) hfin[0][n16 * 52 + u] = h1s[i];   // h1(T-1) f32
        }
#pragma unroll
        for (int i = 0; i < 2; ++i) if (i < nm2) {
            f4 a = {0.f, 0.f, 0.f, 0.f}, b = {0.f, 0.f, 0.f, 0.f};
            a = MF(WfM2[i][0], H20, a); a = MF(WfM2[i][1], H21, a);
            b = MF(WfM2[i][2], H10, b); b = MF(WfM2[i][3], H11, b);
            a = a + b;
            if (stlane) *(f4*)(gbuf2 + s2o[i]) = a;                  // G2(T-1) + out row
            int u = 4 * m2t[i] + q;
            if (n16 < 8 && u < HH) hfin[1][n16 * 52 + u] = h2s[i];   // h2(T-2) f32
        }
    }
    __syncthreads();

    float h1p = hfin[0][w * 52 + il];   // h1(T-1)
    float h2p = hfin[1][w * 52 + il];   // h2(T-2)
    const float* gl1 = gbuf1 + il * US + 4 * w;
    const float* gl2 = gbuf2 + il * US + 4 * w;
    const int or2 = 51 * US;
    _Float16* fh1 = h1T[fbi];
    _Float16* fh2 = h2T[fbi];

    // out(T-2) patch (hoisted out of the loop; gbuf2 valid since transition)
    if (lane == 0) obufL[w * 64 + ((T - 2) & 63)] = gbuf2[or2 + 4 * w];

// feedback step: P1 (e2 -> out -> e1) + barrier + P2 (matmuls) + optional flush + barrier
#define FB_STEP(T_, DOFLUSH)                                                   \
    {                                                                          \
        f4 G1 = *(const f4*)gl1;                                               \
        f4 G2 = *(const f4*)gl2;                                               \
        float r2 = sigm(G2[0]), z2 = sigm(G2[1]);                              \
        float n2 = tanh_fast(fmaf(r2, G2[2], G2[3]));                          \
        float hh2 = fmaf(z2, h2p - n2, n2); h2p = hh2;                         \
        float p = 0.0f;                                                        \
        if (li) { fh2[w * 72 + il] = (_Float16)hh2; p = hh2 * wl; }            \
        float outv = wave_sum(p) + blv;                                        \
        if (lane == 0) obufL[w * 64 + (((T_) - 1) & 63)] = outv;               \
        float r = sigm(fmaf(outv, wr1, G1[0]));                                \
        float z = sigm(fmaf(outv, wz1, G1[1]));                                \
        float n = tanh_fast(fmaf(r, G1[2], fmaf(outv, wn1, G1[3])));           \
        float hh1 = fmaf(z, h1p - n, n); h1p = hh1;                            \
        if (li) fh1[w * 72 + il] = (_Float16)hh1;                              \
        LBAR();                                                                \
        {                                                                      \
            half8 H10 = *(const half8*)(fh1 + ro0);                            \
            half8 H11 = *(const half8*)(fh1 + ro1);                            \
            half8 H20 = *(const half8*)(fh2 + ro0);                            \
            half8 H21 = *(const half8*)(fh2 + ro1);                            \
            _Pragma("unroll")                                                  \
            for (int i = 0; i < 2; ++i) if (i < nm1) {                         \
                f4 a = {0.f, 0.f, 0.f, 0.f};                                   \
                a = MF(WfM1[i][0], H10, a); a = MF(WfM1[i][1], H11, a);        \
                if (stlane) *(f4*)(gbuf1 + s1o[i]) = a;                        \
            }                                                                  \
            _Pragma("unroll")                                                  \
            for (int i = 0; i < 2; ++i) if (i < nm2) {                         \
                f4 a = {0.f, 0.f, 0.f, 0.f}, b = {0.f, 0.f, 0.f, 0.f};         \
                a = MF(WfM2[i][0], H20, a); a = MF(WfM2[i][1], H21, a);        \
                b = MF(WfM2[i][2], H10, b); b = MF(WfM2[i][3], H11, b);        \
                a = a + b;                                                     \
                if (stlane) *(f4*)(gbuf2 + s2o[i]) = a;                        \
            }                                                                  \
        }                                                                      \
        if ((DOFLUSH) && w >= 6 && ((T_) & 31) == 0) {                         \
            int fb = (T_) - 32;                                                \
            _Pragma("unroll")                                                  \
            for (int k2 = 0; k2 < 2; ++k2) {                                   \
                int et = ((w - 6) << 7) + (k2 << 6) + lane;                    \
                int b2 = et >> 5, tt = et & 31;                                \
                storef(dout, (size_t)(bg0 + b2) * TF + fb + tt,                \
                       obufL[b2 * 64 + ((fb + tt) & 63)], isbf);               \
            }                                                                  \
        }                                                                      \
        LBAR();                                                                \
    }

    // ================= FEEDBACK (unrolled x2; TF-T even; flush only on even t) =================
    for (int t = T; t < TF; t += 2) {
        FB_STEP(t, true);
        FB_STEP(t + 1, false);
    }

    // ---- epilogue: e2(TF-1) + out(TF-1) + tail flush ----
    {
        f4 G2 = *(const f4*)gl2;
        float p = 0.0f;
        float r2 = sigm(G2[0]), z2 = sigm(G2[1]);
        float n2 = tanh_fast(fmaf(r2, G2[2], G2[3]));
        float h = fmaf(z2, h2p - n2, n2);
        if (li) p = h * wl;
        float osum = wave_sum(p) + blv;
        if (lane == 0) obufL[w * 64 + ((TF - 1) & 63)] = osum;
    }
    __syncthreads();
    {
        int base = (TF - 1) & ~31, rem = TF - base;
        if (tid < BPB * 32) {
            int b2 = tid >> 5, tt = tid & 31;
            if (tt < rem)
                storef(dout, (size_t)(bg0 + b2) * TF + base + tt, obufL[b2 * 64 + ((base + tt) & 63)], isbf);
        }
    }
}

extern "C" void kernel_launch(void* const* d_in, const int* in_sizes, int n_in,
                              void* d_out, int out_size, void* d_ws, size_t ws_size,
                              hipStream_t stream) {
    const int B = 2048;
    const int T = in_sizes[0] / B;   // 1000
    const int TF = out_size / B;     // 2000
    gru_kernel<<<dim3(B / BPB), dim3(TPB), 0, stream>>>(
        d_in[0], d_in[1], d_in[2], d_in[3], d_in[4], d_in[5],
        d_in[6], d_in[7], d_in[8], d_in[9], d_in[10],
        d_out, T, TF);
}

// Round 14
// 1452.690 us; speedup vs baseline: 1.1882x; 1.0073x over previous
//
#include <hip/hip_runtime.h>
#include <hip/hip_bf16.h>

#define HH 51
#define TPB 1024    // 16 waves; 1 block/CU. Encode: fused 1-phase/step. Feedback: 2-phase (P1 on waves 0-7).
#define BPB 8
#define US 36       // unit stride (floats) in gate buffers (feedback path)

typedef _Float16 half8 __attribute__((ext_vector_type(8)));
typedef float f4 __attribute__((ext_vector_type(4)));

// Light barrier: drain LDS only; global stores / reg-dest loads stay in flight.
#define LBAR() asm volatile("s_waitcnt lgkmcnt(0)\ns_barrier" ::: "memory")

__device__ __forceinline__ float bf2f(unsigned short u) {
    return __uint_as_float(((unsigned)u) << 16);
}
__device__ __forceinline__ float loadf(const void* p, size_t i, bool bf) {
    return bf ? bf2f(((const unsigned short*)p)[i]) : ((const float*)p)[i];
}
__device__ __forceinline__ void storef(void* p, size_t i, float v, bool bf) {
    if (bf) ((__hip_bfloat16*)p)[i] = __float2bfloat16(v);
    else    ((float*)p)[i] = v;
}
__device__ __forceinline__ float sigm(float v) {
    return __builtin_amdgcn_rcpf(1.0f + __expf(-v));
}
__device__ __forceinline__ float tanh_fast(float v) {
    return fmaf(2.0f, __builtin_amdgcn_rcpf(1.0f + __expf(-2.0f * v)), -1.0f);
}
__device__ __forceinline__ f4 MF(half8 a, half8 b, f4 c) {
    return __builtin_amdgcn_mfma_f32_16x16x32_f16(a, b, c, 0, 0, 0);
}
// wave64 sum via DPP (verified), result uniform across lanes
__device__ __forceinline__ float wave_sum(float x) {
    float s = x, t;
    t = __builtin_bit_cast(float, __builtin_amdgcn_update_dpp(0, __builtin_bit_cast(int, s), 0x111, 0xf, 0xf, true)); s += t;
    t = __builtin_bit_cast(float, __builtin_amdgcn_update_dpp(0, __builtin_bit_cast(int, s), 0x112, 0xf, 0xf, true)); s += t;
    t = __builtin_bit_cast(float, __builtin_amdgcn_update_dpp(0, __builtin_bit_cast(int, s), 0x114, 0xf, 0xf, true)); s += t;
    t = __builtin_bit_cast(float, __builtin_amdgcn_update_dpp(0, __builtin_bit_cast(int, s), 0x118, 0xf, 0xf, true)); s += t;
    t = __builtin_bit_cast(float, __builtin_amdgcn_update_dpp(0, __builtin_bit_cast(int, s), 0x142, 0xa, 0xf, true)); s += t;
    t = __builtin_bit_cast(float, __builtin_amdgcn_update_dpp(0, __builtin_bit_cast(int, s), 0x143, 0xc, 0xf, true)); s += t;
    return __builtin_bit_cast(float, __builtin_amdgcn_readlane(__builtin_bit_cast(int, s), 63));
}
__device__ __forceinline__ float rdlane(float v, int idx) {
    return __builtin_bit_cast(float, __builtin_amdgcn_readlane(__builtin_bit_cast(int, v), idx));
}

__global__ __launch_bounds__(TPB, 1) void gru_kernel(
    const void* __restrict__ xg,
    const void* __restrict__ wih1, const void* __restrict__ whh1,
    const void* __restrict__ bih1, const void* __restrict__ bhh1,
    const void* __restrict__ wih2, const void* __restrict__ whh2,
    const void* __restrict__ bih2, const void* __restrict__ bhh2,
    const void* __restrict__ wlin, const void* __restrict__ blin_p,
    void* __restrict__ dout, int T, int TF)
{
    // Rows 4-interleaved: staged row r = 4*unit + slot.
    //  M1: (r_full, z_full, n_h, n_i) — wih1 col53, biases col52, Whh1 cols 0-50
    //  M2: (r2, z2, n2_h, n2_i) over K=128: [h2|bias ; h1]; out row 204 (wl, blv@52)
    __shared__ __align__(16) _Float16 stg[208 * 64];     // 26624 B
    __shared__ __align__(16) float gbuf1[52 * US];       // feedback gates layer 1
    __shared__ __align__(16) float gbuf2[52 * US];       // feedback gates layer 2 (+ out @ unit 51)
    __shared__ __align__(16) _Float16 h1T[2][16 * 72];   // double-buffered h1; k52=1, k53=x-fold
    __shared__ __align__(16) _Float16 h2T[2][16 * 72];   // double-buffered h2; k52=1
    __shared__ float obufL[BPB * 64];                    // out ring, 64 deep
    __shared__ float hfin[2][BPB * 52];                  // f32 h-state handoff at transition

    const int tid = threadIdx.x, w = tid >> 6, lane = tid & 63;
    const int n16 = lane & 15, q = lane >> 4;
    const bool li = lane < HH;
    const int il = li ? lane : HH - 1;
    const int bg0 = blockIdx.x * BPB;
    const bool bw = (w < 8);                 // batch-owning waves
    const int myb = bg0 + (w & 7);

    // runtime dtype detection (fp32 vs bf16), uniform
    bool isbf;
    {
        const unsigned short* u = (const unsigned short*)whh1;
        int ok = 1;
#pragma unroll
        for (int k = 0; k < 16; ++k) {
            unsigned e = (u[2 * k] >> 7) & 0xFF;
            ok &= (e >= 100 && e <= 125) ? 1 : 0;
        }
        isbf = (ok != 0);
    }

    // lane consts (feedback path + out)
    float wr1 = 0, wz1 = 0, wn1 = 0, wl = 0;
    if (li) {
        wr1 = loadf(wih1, il, isbf);          wz1 = loadf(wih1, HH + il, isbf);
        wn1 = loadf(wih1, 2 * HH + il, isbf); wl = loadf(wlin, il, isbf);
    }
    const float blv = loadf(blin_p, 0, isbf);

    // ---- job assignment: 13 M1 tiles -> waves 0-12 (2 MFMA); 13 M2 tiles -> waves 3-15 (4 MFMA) ----
    const bool hasM1 = (w < 13);
    const bool hasM2 = (w >= 3);
    const int m1tl = w;
    const int m2tl = 15 - w;                 // w=3 -> tile 12 (out row), w=15 -> tile 0
    const int laneoff = q * US + 4 * n16;
    const bool stlane = (n16 < 8);
    const bool obl = (w == 3) && (q == 3) && (n16 < 8);   // out-row lane (tile 12, staged row 204)

    half8 WfM1[2], WfM2[4];

    // ---- stage: pass0 = M1; pass1 = M2 K 0-63 (h2 half); pass2 = M2 K 64-127 (h1 half) ----
#pragma unroll 1
    for (int ps = 0; ps < 3; ++ps) {
        for (int e = tid; e < 208 * 64; e += TPB) {
            int r = e >> 6, k = e & 63;
            int u = r >> 2, g = r & 3;
            float v = 0.0f;
            if (ps == 0) {
                if (u < HH) {
                    if (g < 2) {
                        int gr = g * HH + u;
                        if (k < HH) v = loadf(whh1, (size_t)gr * HH + k, isbf);
                        else if (k == 52) v = loadf(bhh1, gr, isbf) + loadf(bih1, gr, isbf);
                        else if (k == 53) v = loadf(wih1, gr, isbf);
                    } else if (g == 2) {
                        int gr = 2 * HH + u;
                        if (k < HH) v = loadf(whh1, (size_t)gr * HH + k, isbf);
                        else if (k == 52) v = loadf(bhh1, gr, isbf);
                    } else {
                        int gr = 2 * HH + u;
                        if (k == 52) v = loadf(bih1, gr, isbf);
                        else if (k == 53) v = loadf(wih1, gr, isbf);
                    }
                }
            } else if (ps == 1) {
                if (u < HH) {
                    if (g < 2) {
                        int gr = g * HH + u;
                        if (k < HH) v = loadf(whh2, (size_t)gr * HH + k, isbf);
                        else if (k == 52) v = loadf(bhh2, gr, isbf) + loadf(bih2, gr, isbf);
                    } else if (g == 2) {
                        int gr = 2 * HH + u;
                        if (k < HH) v = loadf(whh2, (size_t)gr * HH + k, isbf);
                        else if (k == 52) v = loadf(bhh2, gr, isbf);
                    } else {
                        if (k == 52) v = loadf(bih2, 2 * HH + u, isbf);
                    }
                } else if (r == 204) {   // out row: wl . h2 + blv
                    if (k < HH) v = loadf(wlin, k, isbf);
                    else if (k == 52) v = blv;
                }
            } else {
                if (u < HH) {
                    if (g < 2) {
                        if (k < HH) v = loadf(wih2, (size_t)(g * HH + u) * HH + k, isbf);
                    } else if (g == 3) {
                        if (k < HH) v = loadf(wih2, (size_t)(2 * HH + u) * HH + k, isbf);
                    }
                }
            }
            stg[e] = (_Float16)v;
        }
        __syncthreads();
        if (ps == 0 && hasM1) {
            WfM1[0] = *(const half8*)(stg + (size_t)(16 * m1tl + n16) * 64 + q * 8);
            WfM1[1] = *(const half8*)(stg + (size_t)(16 * m1tl + n16) * 64 + 32 + q * 8);
        } else if (ps == 1 && hasM2) {
            WfM2[0] = *(const half8*)(stg + (size_t)(16 * m2tl + n16) * 64 + q * 8);
            WfM2[1] = *(const half8*)(stg + (size_t)(16 * m2tl + n16) * 64 + 32 + q * 8);
        } else if (ps == 2 && hasM2) {
            WfM2[2] = *(const half8*)(stg + (size_t)(16 * m2tl + n16) * 64 + q * 8);
            WfM2[3] = *(const half8*)(stg + (size_t)(16 * m2tl + n16) * 64 + 32 + q * 8);
        }
        __syncthreads();
    }

    // ---- init state LDS ----
    for (int e = tid; e < 16 * 72; e += TPB) {
        h1T[0][e] = (_Float16)0; h1T[1][e] = (_Float16)0;
        h2T[0][e] = (_Float16)0; h2T[1][e] = (_Float16)0;
    }
    float xreg = 0.0f, xnext = 0.0f;
    if (bw && lane < T) xreg = loadf(xg, (size_t)myb * T + lane, isbf);
    __syncthreads();
    if (tid < 16) {
        h1T[0][tid * 72 + 52] = (_Float16)1.0f; h1T[1][tid * 72 + 52] = (_Float16)1.0f;
        h2T[0][tid * 72 + 52] = (_Float16)1.0f; h2T[1][tid * 72 + 52] = (_Float16)1.0f;
    }
    if (bw && lane == 0) h1T[1][w * 72 + 53] = (_Float16)rdlane(xreg, 0);   // x(0) into phase-0 read buffer
    __syncthreads();

    float h1sv = 0.f, h2sv = 0.f;

    // ---- hoisted lane-invariant offsets/masks ----
    const int ro0 = n16 * 72 + q * 8, ro1 = ro0 + 32;
    const int u1 = 4 * m1tl + q, u2 = 4 * m2tl + q;
    const int wo1 = n16 * 72 + u1, wo2 = n16 * 72 + u2;
    const bool stw1 = hasM1 && (n16 < 8) && (u1 < HH);
    const bool stw2 = hasM2 && (n16 < 8) && (u2 < HH);
    const int s1o = m1tl * 4 * US + laneoff;
    const int s2o = m2tl * 4 * US + laneoff;

// fused encode step body; buffer pointers are compile-time per call site
#define ENC_BODY(T_, H1R, H2R, H1W, H2W, DOM2, DOOUT)                          \
    {                                                                          \
        half8 H10 = *(const half8*)((H1R) + ro0);                              \
        half8 H11 = *(const half8*)((H1R) + ro1);                              \
        {                                                                      \
            int ni = ((T_) + 1) & 63;                                          \
            float xsrc = (ni == 0) ? xnext : xreg;                             \
            float xnv = ((T_) == T - 1) ? 0.0f : rdlane(xsrc, ni);             \
            if (bw && lane == 0) (H1W)[w * 72 + 53] = (_Float16)xnv;           \
        }                                                                      \
        if (hasM1) {                                                           \
            f4 a = {0.f, 0.f, 0.f, 0.f};                                       \
            a = MF(WfM1[0], H10, a); a = MF(WfM1[1], H11, a);                  \
            float r = sigm(a[0]), z = sigm(a[1]);                              \
            float n = tanh_fast(fmaf(r, a[2], a[3]));                          \
            float h = fmaf(z, h1sv - n, n); h1sv = h;                          \
            if (stw1) (H1W)[wo1] = (_Float16)h;                                \
        }                                                                      \
        if ((DOM2) && hasM2) {                                                 \
            half8 H20 = *(const half8*)((H2R) + ro0);                          \
            half8 H21 = *(const half8*)((H2R) + ro1);                          \
            f4 a = {0.f, 0.f, 0.f, 0.f}, b = {0.f, 0.f, 0.f, 0.f};             \
            a = MF(WfM2[0], H20, a); a = MF(WfM2[1], H21, a);                  \
            b = MF(WfM2[2], H10, b); b = MF(WfM2[3], H11, b);                  \
            a = a + b;                                                         \
            if ((DOOUT) && obl)                                                \
                obufL[n16 * 64 + (((T_) - 2) & 63)] = a[0];                    \
            float r2 = sigm(a[0]), z2 = sigm(a[1]);                            \
            float n2 = tanh_fast(fmaf(r2, a[2], a[3]));                        \
            float h = fmaf(z2, h2sv - n2, n2); h2sv = h;                       \
            if (stw2) (H2W)[wo2] = (_Float16)h;                                \
        }                                                                      \
    }

    // ================= ENCODE (unrolled x2; T even) =================
    ENC_BODY(0, h1T[1], h2T[1], h1T[0], h2T[0], false, false);
    if (bw && 64 < T) {
        int src = 64 + lane;
        xnext = (src < T) ? loadf(xg, (size_t)myb * T + src, isbf) : 0.0f;
    }
    LBAR();
    ENC_BODY(1, h1T[0], h2T[0], h1T[1], h2T[1], true, false);
    LBAR();
    for (int t = 2; t < T; t += 2) {
        ENC_BODY(t, h1T[1], h2T[1], h1T[0], h2T[0], true, true);
        if (w < 4 && (t & 31) == 2 && t >= 34) {   // flush [t-34 .. t-3]
            int fb = t - 34;
            int et = (w << 6) + lane;
            int b2 = et >> 5, tt = et & 31;
            storef(dout, (size_t)(bg0 + b2) * TF + fb + tt, obufL[b2 * 64 + ((fb + tt) & 63)], isbf);
        }
        if (bw && (t & 63) == 0) {
            int base = t + 64;
            if (base < T) {
                int src = base + lane;
                xnext = (src < T) ? loadf(xg, (size_t)myb * T + src, isbf) : 0.0f;
            }
        }
        LBAR();
        ENC_BODY(t + 1, h1T[0], h2T[0], h1T[1], h2T[1], true, true);
        if (((t + 1) & 63) == 63) xreg = xnext;
        LBAR();
    }

    // ================= TRANSITION: populate gbuf + f32 h-state handoff =================
    const int fbi = (T + 1) & 1;   // == (T-1)&1
    {
        const _Float16* h1r = h1T[fbi];
        const _Float16* h2r = h2T[fbi];
        half8 H10 = *(const half8*)(h1r + ro0);
        half8 H11 = *(const half8*)(h1r + ro1);
        if (hasM1) {
            f4 a = {0.f, 0.f, 0.f, 0.f};
            a = MF(WfM1[0], H10, a); a = MF(WfM1[1], H11, a);
            if (stlane) *(f4*)(gbuf1 + s1o) = a;                 // G1(T)
            if (n16 < 8 && u1 < HH) hfin[0][n16 * 52 + u1] = h1sv;   // h1(T-1) f32
        }
        if (hasM2) {
            half8 H20 = *(const half8*)(h2r + ro0);
            half8 H21 = *(const half8*)(h2r + ro1);
            f4 a = {0.f, 0.f, 0.f, 0.f}, b = {0.f, 0.f, 0.f, 0.f};
            a = MF(WfM2[0], H20, a); a = MF(WfM2[1], H21, a);
            b = MF(WfM2[2], H10, b); b = MF(WfM2[3], H11, b);
            a = a + b;
            if (stlane) *(f4*)(gbuf2 + s2o) = a;                 // G2(T-1) + out row
            if (n16 < 8 && u2 < HH) hfin[1][n16 * 52 + u2] = h2sv;   // h2(T-2) f32
        }
    }
    __syncthreads();

    float h1p = bw ? hfin[0][w * 52 + il] : 0.0f;   // h1(T-1)
    float h2p = bw ? hfin[1][w * 52 + il] : 0.0f;   // h2(T-2)
    const float* gl1 = gbuf1 + il * US + 4 * (w & 7);
    const float* gl2 = gbuf2 + il * US + 4 * (w & 7);
    const int or2 = 51 * US;
    _Float16* fh1 = h1T[fbi];
    _Float16* fh2 = h2T[fbi];

    // out(T-2) patch (hoisted; gbuf2 valid since transition)
    if (bw && lane == 0) obufL[w * 64 + ((T - 2) & 63)] = gbuf2[or2 + 4 * w];

// feedback step: P1 (waves 0-7: e2 -> out -> e1) + barrier + P2 (matmul jobs) + flush + barrier
#define FB_STEP(T_, DOFLUSH)                                                   \
    {                                                                          \
        if (bw) {                                                              \
            f4 G1 = *(const f4*)gl1;                                           \
            f4 G2 = *(const f4*)gl2;                                           \
            float r2 = sigm(G2[0]), z2 = sigm(G2[1]);                          \
            float n2 = tanh_fast(fmaf(r2, G2[2], G2[3]));                      \
            float hh2 = fmaf(z2, h2p - n2, n2); h2p = hh2;                     \
            float p = 0.0f;                                                    \
            if (li) { fh2[w * 72 + il] = (_Float16)hh2; p = hh2 * wl; }        \
            float outv = wave_sum(p) + blv;                                    \
            if (lane == 0) obufL[w * 64 + (((T_) - 1) & 63)] = outv;           \
            float r = sigm(fmaf(outv, wr1, G1[0]));                            \
            float z = sigm(fmaf(outv, wz1, G1[1]));                            \
            float n = tanh_fast(fmaf(r, G1[2], fmaf(outv, wn1, G1[3])));       \
            float hh1 = fmaf(z, h1p - n, n); h1p = hh1;                        \
            if (li) fh1[w * 72 + il] = (_Float16)hh1;                          \
        }                                                                      \
        LBAR();                                                                \
        {                                                                      \
            half8 H10 = *(const half8*)(fh1 + ro0);                            \
            half8 H11 = *(const half8*)(fh1 + ro1);                            \
            if (hasM1) {                                                       \
                f4 a = {0.f, 0.f, 0.f, 0.f};                                   \
                a = MF(WfM1[0], H10, a); a = MF(WfM1[1], H11, a);              \
                if (stlane) *(f4*)(gbuf1 + s1o) = a;                           \
            }                                                                  \
            if (hasM2) {                                                       \
                half8 H20 = *(const half8*)(fh2 + ro0);                        \
                half8 H21 = *(const half8*)(fh2 + ro1);                        \
                f4 a = {0.f, 0.f, 0.f, 0.f}, b = {0.f, 0.f, 0.f, 0.f};         \
                a = MF(WfM2[0], H20, a); a = MF(WfM2[1], H21, a);              \
                b = MF(WfM2[2], H10, b); b = MF(WfM2[3], H11, b);              \
                a = a + b;                                                     \
                if (stlane) *(f4*)(gbuf2 + s2o) = a;                           \
            }                                                                  \
        }                                                                      \
        if ((DOFLUSH) && w < 4 && ((T_) & 31) == 0) {                          \
            int fb = (T_) - 32;                                                \
            int et = (w << 6) + lane;                                          \
            int b2 = et >> 5, tt = et & 31;                                    \
            storef(dout, (size_t)(bg0 + b2) * TF + fb + tt,                    \
                   obufL[b2 * 64 + ((fb + tt) & 63)], isbf);                   \
        }                                                                      \
        LBAR();                                                                \
    }

    // ================= FEEDBACK (unrolled x2; TF-T even; flush only on even t) =================
    for (int t = T; t < TF; t += 2) {
        FB_STEP(t, true);
        FB_STEP(t + 1, false);
    }

    // ---- epilogue: e2(TF-1) + out(TF-1) + tail flush ----
    if (bw) {
        f4 G2 = *(const f4*)gl2;
        float p = 0.0f;
        float r2 = sigm(G2[0]), z2 = sigm(G2[1]);
        float n2 = tanh_fast(fmaf(r2, G2[2], G2[3]));
        float h = fmaf(z2, h2p - n2, n2);
        if (li) p = h * wl;
        float osum = wave_sum(p) + blv;
        if (lane == 0) obufL[w * 64 + ((TF - 1) & 63)] = osum;
    }
    __syncthreads();
    {
        int base = (TF - 1) & ~31, rem = TF - base;
        if (tid < BPB * 32) {
            int b2 = tid >> 5, tt = tid & 31;
            if (tt < rem)
                storef(dout, (size_t)(bg0 + b2) * TF + base + tt, obufL[b2 * 64 + ((base + tt) & 63)], isbf);
        }
    }
}

extern "C" void kernel_launch(void* const* d_in, const int* in_sizes, int n_in,
                              void* d_out, int out_size, void* d_ws, size_t ws_size,
                              hipStream_t stream) {
    const int B = 2048;
    const int T = in_sizes[0] / B;   // 1000
    const int TF = out_size / B;     // 2000
    gru_kernel<<<dim3(B / BPB), dim3(TPB), 0, stream>>>(
        d_in[0], d_in[1], d_in[2], d_in[3], d_in[4], d_in[5],
        d_in[6], d_in[7], d_in[8], d_in[9], d_in[10],
        d_out, T, TF);
}